// Round 9
// baseline (454.769 us; speedup 1.0000x reference)
//
#include <hip/hip_runtime.h>
#include <hip/hip_bf16.h>
#include <math.h>

typedef __hip_bfloat16 bf16;

#define D_MODEL 1024
#define D_INNER 2048
#define NTOK    4096   // B*L
#define SEQ     2048
#define BSZ     2
#define DSTATE  16
#define DTRANK  64
#define NCH     64
#define CHLEN   32     // SEQ / NCH
#define NPAIR   4096   // BSZ * D_INNER
#define XDS     128    // xdbl row stride (fp32), padded from 96

__device__ __forceinline__ float b2f(bf16 v) { return __bfloat162float(v); }
__device__ __forceinline__ bf16  f2b(float v) { return __float2bfloat16(v); }
__device__ __forceinline__ short f2bs(float v) {
    bf16 h = __float2bfloat16(v);
    short s; __builtin_memcpy(&s, &h, 2); return s;
}

typedef __attribute__((ext_vector_type(8))) short short8;
typedef __attribute__((ext_vector_type(4))) float f32x4;

__device__ __forceinline__ void async_copy16(const void* g, void* l) {
    __builtin_amdgcn_global_load_lds(
        (const __attribute__((address_space(1))) unsigned int*)g,
        (__attribute__((address_space(3))) unsigned int*)l,
        16, 0, 0);
}

// ---------------------------------------------------------------- LayerNorm
__global__ void k_layernorm(const float* __restrict__ x, const float* __restrict__ g,
                            const float* __restrict__ b, bf16* __restrict__ xn) {
    int t = blockIdx.x;
    int tid = threadIdx.x;
    const float* row = x + (size_t)t * D_MODEL;
    float v[4];
    float s = 0.f, q = 0.f;
#pragma unroll
    for (int i = 0; i < 4; ++i) {
        int idx = tid + i * 256;
        v[i] = row[idx];
        s += v[i]; q += v[i] * v[i];
    }
    __shared__ float sh_s[256], sh_q[256];
    sh_s[tid] = s; sh_q[tid] = q;
    __syncthreads();
    for (int o = 128; o > 0; o >>= 1) {
        if (tid < o) { sh_s[tid] += sh_s[tid + o]; sh_q[tid] += sh_q[tid + o]; }
        __syncthreads();
    }
    float mu  = sh_s[0] * (1.f / D_MODEL);
    float var = sh_q[0] * (1.f / D_MODEL) - mu * mu;
    float rs  = rsqrtf(var + 1e-5f);
#pragma unroll
    for (int i = 0; i < 4; ++i) {
        int idx = tid + i * 256;
        float o = (v[i] - mu) * rs * g[idx] + b[idx];
        xn[(size_t)t * D_MODEL + idx] = f2b(o);
    }
}

// ---------------------------------------------------------------- fp32 -> bf16 convert
__global__ void k_f2b(const float* __restrict__ in, short* __restrict__ out) {
    int i = blockIdx.x * 256 + threadIdx.x;
    float4 v = reinterpret_cast<const float4*>(in)[i];
    short4 o;
    o.x = f2bs(v.x); o.y = f2bs(v.y); o.z = f2bs(v.z); o.w = f2bs(v.w);
    reinterpret_cast<short4*>(out)[i] = o;
}

// ---------------------------------------------------------------- zero fp32 buffer
__global__ void k_zero(float* __restrict__ p) {
    int i = blockIdx.x * 256 + threadIdx.x;
    reinterpret_cast<float4*>(p)[i] = (float4){0.f, 0.f, 0.f, 0.f};
}

// --------------------------------------------- xpw (96x2048 fp32) -> padded 128x2048 bf16
__global__ void k_prep_xpw(const float* __restrict__ in, short* __restrict__ out) {
    int i = blockIdx.x * 256 + threadIdx.x;
    int row = i >> 9;
    short4 o;
    if (row < 96) {
        float4 v = reinterpret_cast<const float4*>(in)[i];
        o.x = f2bs(v.x); o.y = f2bs(v.y); o.z = f2bs(v.z); o.w = f2bs(v.w);
    } else {
        o.x = o.y = o.z = o.w = 0;
    }
    reinterpret_cast<short4*>(out)[i] = o;
}

// --------------------------------------------- dr = xdbl[:, 0:64] -> bf16 (4096x64)
__global__ void k_extract_dr(const float* __restrict__ xdbl, short* __restrict__ drb) {
    int i = blockIdx.x * 256 + threadIdx.x;
    int t = i >> 4;
    int jg = (i & 15) * 4;
    float4 v = *reinterpret_cast<const float4*>(&xdbl[(size_t)t * XDS + jg]);
    short4 o;
    o.x = f2bs(v.x); o.y = f2bs(v.y); o.z = f2bs(v.z); o.w = f2bs(v.w);
    *reinterpret_cast<short4*>(&drb[(size_t)t * DTRANK + jg]) = o;
}

// ---------------------------------------------------------------- MFMA GEMM (NT)
// mode 0: split at D_INNER -> Cf fp32 / Cz bf16   (in-proj)
// mode 1: Cout = acc + res (fp32, residual)       (out-proj)
// mode 2: atomicAdd(Cf, acc)                      (xproj, split-K via blockIdx.z)
// mode 3: Cf = softplus(acc + bias[col]) fp32     (delta)
//
// 3-buffer pipeline, raw s_barrier, manual vmcnt: prologue issues tiles 0,1;
// each iter: s_waitcnt vmcnt(4) (own tile-i loads retired, FIFO order) ->
// s_barrier (all waves' tile-i loads landed) -> issue tile i+2 into 3rd buffer
// -> ds_read/MFMA tile i. Loads stay in flight ACROSS the barrier (~2 iters
// of latency hidden). Tail: dummy wrap-around issue keeps vmcnt uniform;
// vmcnt(0) after the loop retires dummies before LDS dealloc.
// LDS bank-conflict XOR swizzle (R7, verified conflict-free) retained.
#define GBK 32
#define BUFE (128 * GBK)     // elements per buffer per matrix (8 KB)
__global__ __launch_bounds__(256) void k_gemm_mfma(
    const short* __restrict__ A, const short* __restrict__ Bw,
    int N, int K, int mode,
    float* __restrict__ Cf, bf16* __restrict__ Cz,
    const float* __restrict__ res, float* __restrict__ Cout,
    const float* __restrict__ bias)
{
    __shared__ short As[3 * BUFE];
    __shared__ short Bs[3 * BUFE];
    const int tid  = threadIdx.x;
    const int lane = tid & 63;
    const int wave = tid >> 6;
    const int wm = wave >> 1, wn = wave & 1;

    // XCD-aware swizzle: g%8 -> XCD; each XCD owns a contiguous n-tile group
    // (weight slice L2-resident); adjacent q share the same m-tile (A reuse).
    int gx, gy;
    {
        int g = blockIdx.y * gridDim.x + blockIdx.x;
        if ((gridDim.x & 7) == 0) {
            int nX = gridDim.x >> 3;
            int xcd = g & 7;
            int q = g >> 3;
            gx = xcd * nX + (q % nX);
            gy = q / nX;
        } else { gx = blockIdx.x; gy = blockIdx.y; }
    }
    const int m0 = gy * 128;
    const int n0 = gx * 128;
    const int lm   = lane & 15;
    const int koff = (((lane >> 4) ^ ((lane >> 1) & 3)) * 8);

    const int srow = tid >> 2;
    const int skc  = (((tid & 3) ^ ((tid >> 3) & 3)) * 8);   // swizzled source chunk
    const size_t a_off0 = (size_t)(m0 + srow) * K + skc;
    const size_t a_off1 = (size_t)(m0 + srow + 64) * K + skc;
    const size_t b_off0 = (size_t)(n0 + srow) * K + skc;
    const size_t b_off1 = (size_t)(n0 + srow + 64) * K + skc;

    f32x4 acc[4][4];
#pragma unroll
    for (int i = 0; i < 4; ++i)
#pragma unroll
        for (int j = 0; j < 4; ++j)
            acc[i][j] = (f32x4){0.f, 0.f, 0.f, 0.f};

    const int kchunk = K / gridDim.z;
    const int kbeg = blockIdx.z * kchunk;
    const int kend = kbeg + kchunk;
    const int ntiles = kchunk / GBK;

    // prologue: stage tiles 0 and 1 into buffers 0 and 1
#pragma unroll
    for (int p = 0; p < 2; ++p) {
        char* a_dst = (char*)As + p * (BUFE * 2) + tid * 16;
        char* b_dst = (char*)Bs + p * (BUFE * 2) + tid * 16;
        int kp = kbeg + p * GBK;
        async_copy16(A + a_off0 + kp, a_dst);
        async_copy16(A + a_off1 + kp, a_dst + 4096);
        async_copy16(Bw + b_off0 + kp, b_dst);
        async_copy16(Bw + b_off1 + kp, b_dst + 4096);
    }

    int cb = 0, nb = 2;
    for (int it = 0; it < ntiles; ++it) {
        asm volatile("s_waitcnt vmcnt(4)" ::: "memory");   // own tile-it loads done
        __builtin_amdgcn_s_barrier();                      // everyone's tile-it loads done
        int kn = kbeg + (it + 2) * GBK;
        if (kn >= kend) kn = kbeg;                         // dummy wrap: uniform vmcnt
        {
            char* a_dst = (char*)As + nb * (BUFE * 2) + tid * 16;
            char* b_dst = (char*)Bs + nb * (BUFE * 2) + tid * 16;
            async_copy16(A + a_off0 + kn, a_dst);
            async_copy16(A + a_off1 + kn, a_dst + 4096);
            async_copy16(Bw + b_off0 + kn, b_dst);
            async_copy16(Bw + b_off1 + kn, b_dst + 4096);
        }

        const short* Ab = As + cb * BUFE;
        const short* Bb = Bs + cb * BUFE;
        short8 af[4], bf[4];
#pragma unroll
        for (int t = 0; t < 4; ++t) {
            af[t] = *reinterpret_cast<const short8*>(&Ab[(wm * 64 + t * 16 + lm) * GBK + koff]);
            bf[t] = *reinterpret_cast<const short8*>(&Bb[(wn * 64 + t * 16 + lm) * GBK + koff]);
        }
#pragma unroll
        for (int tm = 0; tm < 4; ++tm)
#pragma unroll
            for (int tn = 0; tn < 4; ++tn)
                acc[tm][tn] = __builtin_amdgcn_mfma_f32_16x16x32_bf16(
                    af[tm], bf[tn], acc[tm][tn], 0, 0, 0);
        cb = (cb == 2) ? 0 : cb + 1;
        nb = (nb == 2) ? 0 : nb + 1;
    }
    asm volatile("s_waitcnt vmcnt(0)" ::: "memory");       // retire dummy DMAs (LDS dealloc safety)

    const int rq = (lane >> 4) * 4;
#pragma unroll
    for (int tm = 0; tm < 4; ++tm) {
#pragma unroll
        for (int tn = 0; tn < 4; ++tn) {
            f32x4 v = acc[tm][tn];
            int col = n0 + wn * 64 + tn * 16 + lm;
#pragma unroll
            for (int r = 0; r < 4; ++r) {
                int row = m0 + wm * 64 + tm * 16 + rq + r;
                float val = v[r];
                if (mode == 0) {
                    if (col < D_INNER) Cf[(size_t)row * D_INNER + col] = val;
                    else               Cz[(size_t)row * D_INNER + (col - D_INNER)] = f2b(val);
                } else if (mode == 1) {
                    Cout[(size_t)row * N + col] = val + res[(size_t)row * N + col];
                } else if (mode == 2) {
                    atomicAdd(&Cf[(size_t)row * N + col], val);
                } else {
                    float a = val + bias[col];
                    float sp = (a > 20.f) ? a : log1pf(expf(a));
                    Cf[(size_t)row * N + col] = sp;
                }
            }
        }
    }
}

// ------------------------------------------------- causal depthwise conv + SiLU
__global__ void k_conv(const float* __restrict__ xc, const float* __restrict__ cw,
                       const float* __restrict__ cb, bf16* __restrict__ xcs) {
    size_t idx = (size_t)blockIdx.x * blockDim.x + threadIdx.x;
    int d = (int)(idx & (D_INNER - 1));
    int l = (int)((idx >> 11) & (SEQ - 1));
    float w0 = cw[d * 4 + 0], w1 = cw[d * 4 + 1];
    float w2 = cw[d * 4 + 2], w3 = cw[d * 4 + 3];
    const float* base = xc + idx;
    float acc = cb[d] + w3 * base[0];
    if (l >= 1) acc += w2 * base[-(int)D_INNER];
    if (l >= 2) acc += w1 * base[-2 * (int)D_INNER];
    if (l >= 3) acc += w0 * base[-3 * (int)D_INNER];
    xcs[idx] = f2b(acc / (1.f + __expf(-acc)));   // silu
}

// ------------------------------------------------- scan pass A: per-chunk partials
__global__ __launch_bounds__(256) void k_scan_partialB(
    const float* __restrict__ delta, const bf16* __restrict__ xcs,
    const float* __restrict__ xdbl, const float* __restrict__ A_log,
    bf16* __restrict__ chs, float* __restrict__ sumdl)
{
    __shared__ float Bsh[CHLEN][16];
    const int tid = threadIdx.x;
    const int d = blockIdx.x * 256 + tid;
    const int chunk = blockIdx.y;
    const int b = blockIdx.z;
    const size_t tbase = (size_t)b * SEQ + (size_t)chunk * CHLEN;

    if (tid < 128) {
        int t = tid >> 2, j = (tid & 3) * 4;
        float4 v = *reinterpret_cast<const float4*>(&xdbl[(tbase + t) * XDS + 64 + j]);
        *reinterpret_cast<float4*>(&Bsh[t][j]) = v;
    }
    float An[16];
#pragma unroll
    for (int j = 0; j < 4; ++j) {
        float4 v = *reinterpret_cast<const float4*>(&A_log[(size_t)d * DSTATE + j * 4]);
        An[j * 4 + 0] = -__expf(v.x); An[j * 4 + 1] = -__expf(v.y);
        An[j * 4 + 2] = -__expf(v.z); An[j * 4 + 3] = -__expf(v.w);
    }
    __syncthreads();

    float s[16];
#pragma unroll
    for (int n = 0; n < 16; ++n) s[n] = 0.f;
    float sd = 0.f;
    for (int t = 0; t < CHLEN; ++t) {
        size_t gt = tbase + t;
        float dl = delta[gt * D_INNER + d];
        float u  = b2f(xcs[gt * D_INNER + d]);
        float dlu = dl * u;
        sd += dl;
#pragma unroll
        for (int n = 0; n < 16; ++n) {
            float dA = __expf(dl * An[n]);
            s[n] = fmaf(dA, s[n], dlu * Bsh[t][n]);
        }
    }
    const int pair = b * D_INNER + d;
    bf16* co = chs + ((size_t)pair * NCH + chunk) * DSTATE;
#pragma unroll
    for (int n = 0; n < 16; ++n) co[n] = f2b(s[n]);
    sumdl[(size_t)pair * NCH + chunk] = sd;
}

// ------------------------------------------------- scan pass B: chunk-prefix combine
// sst ALIASES chs: read chunk-sum before writing entry state (same thread+element).
__global__ void k_scan_combineB(const bf16* __restrict__ chs, const float* __restrict__ sumdl,
                                const float* __restrict__ A_log, bf16* __restrict__ sst) {
    int idx = blockIdx.x * 256 + threadIdx.x;
    int pair = idx >> 4;
    int n = idx & 15;
    int d = pair & (D_INNER - 1);
    float An = -__expf(A_log[(size_t)d * DSTATE + n]);
    float s = 0.f;
    for (int c = 0; c < NCH; ++c) {
        size_t o = ((size_t)pair * NCH + c) * DSTATE + n;
        float loc = b2f(chs[o]);
        float ap = __expf(An * sumdl[(size_t)pair * NCH + c]);
        sst[o] = f2b(s);
        s = fmaf(ap, s, loc);
    }
}

// ------------------------------------------------- scan pass C: final y + gate
// yf aliases zbuf elementwise (same-thread read-then-write).
__global__ __launch_bounds__(256) void k_scan_finalB(
    const float* __restrict__ delta, const bf16* __restrict__ xcs,
    const float* __restrict__ xdbl, const bf16* __restrict__ zbuf,
    const float* __restrict__ A_log, const float* __restrict__ Dp,
    const bf16* __restrict__ sst, bf16* __restrict__ yf)
{
    __shared__ float BC[CHLEN][32];   // [t][0:16]=B, [t][16:32]=C
    const int tid = threadIdx.x;
    const int d = blockIdx.x * 256 + tid;
    const int chunk = blockIdx.y;
    const int b = blockIdx.z;
    const size_t tbase = (size_t)b * SEQ + (size_t)chunk * CHLEN;

    {
        int t = tid >> 3, j = (tid & 7) * 4;
        float4 v = *reinterpret_cast<const float4*>(&xdbl[(tbase + t) * XDS + 64 + j]);
        *reinterpret_cast<float4*>(&BC[t][j]) = v;
    }
    float An[16];
#pragma unroll
    for (int j = 0; j < 4; ++j) {
        float4 v = *reinterpret_cast<const float4*>(&A_log[(size_t)d * DSTATE + j * 4]);
        An[j * 4 + 0] = -__expf(v.x); An[j * 4 + 1] = -__expf(v.y);
        An[j * 4 + 2] = -__expf(v.z); An[j * 4 + 3] = -__expf(v.w);
    }
    const int pair = b * D_INNER + d;
    float s[16];
    const bf16* so = sst + ((size_t)pair * NCH + chunk) * DSTATE;
#pragma unroll
    for (int n = 0; n < 16; ++n) s[n] = b2f(so[n]);
    const float Dv = Dp[d];
    __syncthreads();

    for (int t = 0; t < CHLEN; ++t) {
        size_t gt = tbase + t;
        float dl = delta[gt * D_INNER + d];
        float u  = b2f(xcs[gt * D_INNER + d]);
        float dlu = dl * u;
        float y = 0.f;
#pragma unroll
        for (int n = 0; n < 16; ++n) {
            float dA = __expf(dl * An[n]);
            s[n] = fmaf(dA, s[n], dlu * BC[t][n]);
            y = fmaf(s[n], BC[t][16 + n], y);
        }
        float zv = b2f(zbuf[gt * D_INNER + d]);
        float sz = zv / (1.f + __expf(-zv));
        yf[gt * D_INNER + d] = f2b((y + u * Dv) * sz);
    }
}

// ---------------------------------------------------------------- launch
extern "C" void kernel_launch(void* const* d_in, const int* in_sizes, int n_in,
                              void* d_out, int out_size, void* d_ws, size_t ws_size,
                              hipStream_t stream) {
    const float* x      = (const float*)d_in[0];
    const float* ln_g   = (const float*)d_in[1];
    const float* ln_b   = (const float*)d_in[2];
    const float* W_in   = (const float*)d_in[3];
    const float* conv_w = (const float*)d_in[4];
    const float* conv_b = (const float*)d_in[5];
    const float* A_log  = (const float*)d_in[6];
    const float* D_par  = (const float*)d_in[7];
    const float* xpw    = (const float*)d_in[8];
    const float* dtw    = (const float*)d_in[9];
    const float* dtb    = (const float*)d_in[10];
    const float* W_out  = (const float*)d_in[11];
    float* out = (float*)d_out;

    char* ws = (char*)d_ws;
    // workspace (~79.9 MB), stage-lifetime aliased (unchanged from R5):
    bf16*  xn    = (bf16*)(ws + 0);
    bf16*  chs   = (bf16*)(ws + 0);
    bf16*  sst   = chs;
    float* xc    = (float*)(ws + 8388608);
    float* delta = xc;
    short* wOutb = (short*)(ws + 8388608);
    bf16*  z     = (bf16*)(ws + 41943040);
    bf16*  yf    = z;
    short* wInb  = (short*)(ws + 58720256);
    bf16*  xcs   = (bf16*)(ws + 58720256);
    float* xdbl  = (float*)(ws + 75497472);
    float* sumdl = (float*)(ws + 77594624);
    short* drb   = (short*)(ws + 78643200);
    short* dtwb  = (short*)(ws + 79167488);
    short* xpwb  = (short*)(ws + 79429632);

    k_layernorm<<<NTOK, 256, 0, stream>>>(x, ln_g, ln_b, xn);
    k_f2b<<<(2 * D_INNER * D_MODEL / 4) / 256, 256, 0, stream>>>(W_in, wInb);
    // in-proj GEMM: 4096 x 4096 x 1024
    k_gemm_mfma<<<dim3(2 * D_INNER / 128, NTOK / 128, 1), 256, 0, stream>>>(
        (const short*)xn, wInb, 2 * D_INNER, D_MODEL, 0, xc, z, nullptr, nullptr, nullptr);
    k_conv<<<(NTOK * D_INNER) / 256, 256, 0, stream>>>(xc, conv_w, conv_b, xcs);
    // xproj GEMM: 4096 x 128 x 2048, split-K=8 atomic
    k_zero<<<(NTOK * XDS / 4) / 256, 256, 0, stream>>>(xdbl);
    k_prep_xpw<<<(128 * D_INNER / 4) / 256, 256, 0, stream>>>(xpw, xpwb);
    k_gemm_mfma<<<dim3(1, NTOK / 128, 8), 256, 0, stream>>>(
        (const short*)xcs, xpwb, XDS, D_INNER, 2, xdbl, nullptr, nullptr, nullptr, nullptr);
    // delta GEMM: 4096 x 2048 x 64, softplus epilogue
    k_extract_dr<<<(NTOK * DTRANK / 4) / 256, 256, 0, stream>>>(xdbl, drb);
    k_f2b<<<(D_INNER * DTRANK / 4) / 256, 256, 0, stream>>>(dtw, dtwb);
    k_gemm_mfma<<<dim3(D_INNER / 128, NTOK / 128, 1), 256, 0, stream>>>(
        drb, dtwb, D_INNER, DTRANK, 3, delta, nullptr, nullptr, nullptr, dtb);
    // selective scan (3-pass, register-state formulation)
    k_scan_partialB<<<dim3(D_INNER / 256, NCH, BSZ), 256, 0, stream>>>(
        delta, xcs, xdbl, A_log, chs, sumdl);
    k_scan_combineB<<<(NPAIR * DSTATE) / 256, 256, 0, stream>>>(chs, sumdl, A_log, sst);
    k_scan_finalB<<<dim3(D_INNER / 256, NCH, BSZ), 256, 0, stream>>>(
        delta, xcs, xdbl, z, A_log, D_par, sst, yf);
    // out-proj GEMM: 4096 x 1024 x 2048 + residual
    k_f2b<<<(D_MODEL * D_INNER / 4) / 256, 256, 0, stream>>>(W_out, wOutb);
    k_gemm_mfma<<<dim3(D_MODEL / 128, NTOK / 128, 1), 256, 0, stream>>>(
        (const short*)yf, wOutb, D_MODEL, D_INNER, 1, nullptr, nullptr, x, out, nullptr);
}

// Round 10
// 383.622 us; speedup vs baseline: 1.1855x; 1.1855x over previous
//
#include <hip/hip_runtime.h>
#include <hip/hip_bf16.h>
#include <math.h>

typedef __hip_bfloat16 bf16;

#define D_MODEL 1024
#define D_INNER 2048
#define NTOK    4096   // B*L
#define SEQ     2048
#define BSZ     2
#define DSTATE  16
#define DTRANK  64
#define NCH     64
#define CHLEN   32     // SEQ / NCH
#define NPAIR   4096   // BSZ * D_INNER
#define XDS     128    // xdbl row stride (fp32), padded from 96

__device__ __forceinline__ float b2f(bf16 v) { return __bfloat162float(v); }
__device__ __forceinline__ bf16  f2b(float v) { return __float2bfloat16(v); }
__device__ __forceinline__ short f2bs(float v) {
    bf16 h = __float2bfloat16(v);
    short s; __builtin_memcpy(&s, &h, 2); return s;
}

typedef __attribute__((ext_vector_type(8))) short short8;
typedef __attribute__((ext_vector_type(4))) float f32x4;

__device__ __forceinline__ void async_copy16(const void* g, void* l) {
    __builtin_amdgcn_global_load_lds(
        (const __attribute__((address_space(1))) unsigned int*)g,
        (__attribute__((address_space(3))) unsigned int*)l,
        16, 0, 0);
}

// ---------------------------------------------------------------- fused prep
// blocks [0,4096): LayerNorm; [4096,8192): f2b W_in; [8192,8448): prep xpw;
// [8448,8576): f2b dtw; [8576,9088): zero xdbl. Uniform branch per block.
__global__ void k_prep(const float* __restrict__ x, const float* __restrict__ g,
                       const float* __restrict__ b, bf16* __restrict__ xn,
                       const float* __restrict__ W_in, short* __restrict__ wInb,
                       const float* __restrict__ xpw, short* __restrict__ xpwb,
                       const float* __restrict__ dtw, short* __restrict__ dtwb,
                       float* __restrict__ xdbl) {
    int bid = blockIdx.x;
    int tid = threadIdx.x;
    if (bid < 4096) {                       // ---- LayerNorm, one block per token
        int t = bid;
        const float* row = x + (size_t)t * D_MODEL;
        float v[4];
        float s = 0.f, q = 0.f;
#pragma unroll
        for (int i = 0; i < 4; ++i) {
            int idx = tid + i * 256;
            v[i] = row[idx];
            s += v[i]; q += v[i] * v[i];
        }
        __shared__ float sh_s[256], sh_q[256];
        sh_s[tid] = s; sh_q[tid] = q;
        __syncthreads();
        for (int o = 128; o > 0; o >>= 1) {
            if (tid < o) { sh_s[tid] += sh_s[tid + o]; sh_q[tid] += sh_q[tid + o]; }
            __syncthreads();
        }
        float mu  = sh_s[0] * (1.f / D_MODEL);
        float var = sh_q[0] * (1.f / D_MODEL) - mu * mu;
        float rs  = rsqrtf(var + 1e-5f);
#pragma unroll
        for (int i = 0; i < 4; ++i) {
            int idx = tid + i * 256;
            float o = (v[i] - mu) * rs * g[idx] + b[idx];
            xn[(size_t)t * D_MODEL + idx] = f2b(o);
        }
    } else if (bid < 8192) {                // ---- f2b W_in (float4 per thread)
        int i = (bid - 4096) * 256 + tid;
        float4 v = reinterpret_cast<const float4*>(W_in)[i];
        short4 o;
        o.x = f2bs(v.x); o.y = f2bs(v.y); o.z = f2bs(v.z); o.w = f2bs(v.w);
        reinterpret_cast<short4*>(wInb)[i] = o;
    } else if (bid < 8448) {                // ---- xpw 96x2048 -> padded 128x2048 bf16
        int i = (bid - 8192) * 256 + tid;
        int row = i >> 9;
        short4 o;
        if (row < 96) {
            float4 v = reinterpret_cast<const float4*>(xpw)[i];
            o.x = f2bs(v.x); o.y = f2bs(v.y); o.z = f2bs(v.z); o.w = f2bs(v.w);
        } else { o.x = o.y = o.z = o.w = 0; }
        reinterpret_cast<short4*>(xpwb)[i] = o;
    } else if (bid < 8576) {                // ---- f2b dtw
        int i = (bid - 8448) * 256 + tid;
        float4 v = reinterpret_cast<const float4*>(dtw)[i];
        short4 o;
        o.x = f2bs(v.x); o.y = f2bs(v.y); o.z = f2bs(v.z); o.w = f2bs(v.w);
        reinterpret_cast<short4*>(dtwb)[i] = o;
    } else {                                // ---- zero xdbl
        int i = (bid - 8576) * 256 + tid;
        reinterpret_cast<float4*>(xdbl)[i] = (float4){0.f, 0.f, 0.f, 0.f};
    }
}

// ---------------------------------------------------------------- fp32 -> bf16 convert
__global__ void k_f2b(const float* __restrict__ in, short* __restrict__ out) {
    int i = blockIdx.x * 256 + threadIdx.x;
    float4 v = reinterpret_cast<const float4*>(in)[i];
    short4 o;
    o.x = f2bs(v.x); o.y = f2bs(v.y); o.z = f2bs(v.z); o.w = f2bs(v.w);
    reinterpret_cast<short4*>(out)[i] = o;
}

// --------------------------------------------- dr = xdbl[:, 0:64] -> bf16 (4096x64)
__global__ void k_extract_dr(const float* __restrict__ xdbl, short* __restrict__ drb) {
    int i = blockIdx.x * 256 + threadIdx.x;
    int t = i >> 4;
    int jg = (i & 15) * 4;
    float4 v = *reinterpret_cast<const float4*>(&xdbl[(size_t)t * XDS + jg]);
    short4 o;
    o.x = f2bs(v.x); o.y = f2bs(v.y); o.z = f2bs(v.z); o.w = f2bs(v.w);
    *reinterpret_cast<short4*>(&drb[(size_t)t * DTRANK + jg]) = o;
}

// ---------------------------------------------------------------- MFMA GEMM (NT)
// 128 x NT block tile (NT = 128 or 64), BK=32, R8 double-buffered single-barrier
// K-loop, R7 XOR bank swizzle. M always 4096.
// mode 0: split at D_INNER -> Cf fp32 / Cz bf16   (in-proj)
// mode 1: Cout = acc + res (fp32, residual)
// mode 2: atomicAdd(Cf, acc)                      (xproj, split-K via blockIdx.z)
// mode 3: Cf = softplus(acc + bias[col]) fp32     (delta)
// mode 4: Cf[z*M*N + row*N + col] = acc           (split-K partials, no atomics)
#define GBK 32
template<int NT>
__global__ __launch_bounds__(256) void k_gemm_mfma(
    const short* __restrict__ A, const short* __restrict__ Bw,
    int N, int K, int mode,
    float* __restrict__ Cf, bf16* __restrict__ Cz,
    const float* __restrict__ res, float* __restrict__ Cout,
    const float* __restrict__ bias)
{
    constexpr int ABUF = 128 * GBK;            // shorts per A buffer (8 KB)
    constexpr int BBUF = NT * GBK;             // shorts per B buffer
    constexpr int AF   = (NT == 128) ? 4 : 2;  // row frags per wave
    __shared__ short As[2 * ABUF];
    __shared__ short Bs[2 * BBUF];
    const int tid  = threadIdx.x;
    const int lane = tid & 63;
    const int wave = tid >> 6;
    const int rowbase = (NT == 128) ? (wave >> 1) * 64 : wave * 32;
    const int colbase = (NT == 128) ? (wave & 1) * 64 : 0;
    const int m0 = blockIdx.y * 128;
    const int n0 = blockIdx.x * NT;
    const int lm = lane & 15;
    const int koff = (((lane >> 4) ^ ((lane >> 1) & 3)) * 8);

    const int srow = tid >> 2;                              // 0..63
    const int skc  = (((tid & 3) ^ ((tid >> 3) & 3)) * 8);  // swizzled source chunk
    const size_t a_off0 = (size_t)(m0 + srow) * K + skc;
    const size_t a_off1 = (size_t)(m0 + srow + 64) * K + skc;
    const size_t b_off0 = (size_t)(n0 + srow) * K + skc;
    size_t b_off1 = 0;
    if constexpr (NT == 128) b_off1 = (size_t)(n0 + srow + 64) * K + skc;

    f32x4 acc[AF][4];
#pragma unroll
    for (int i = 0; i < AF; ++i)
#pragma unroll
        for (int j = 0; j < 4; ++j)
            acc[i][j] = (f32x4){0.f, 0.f, 0.f, 0.f};

    const int kchunk = K / gridDim.z;
    const int kbeg = blockIdx.z * kchunk;
    const int kend = kbeg + kchunk;

    // prologue: tile 0 into buffer 0
    {
        char* aD = (char*)As + tid * 16;
        char* bD = (char*)Bs + tid * 16;
        async_copy16(A + a_off0 + kbeg, aD);
        async_copy16(A + a_off1 + kbeg, aD + 4096);
        async_copy16(Bw + b_off0 + kbeg, bD);
        if constexpr (NT == 128) async_copy16(Bw + b_off1 + kbeg, bD + 4096);
    }

    int cur = 0;
    for (int k0 = kbeg; k0 < kend; k0 += GBK) {
        __syncthreads();   // buf[cur] ready; compute on buf[cur^1] done
        int k1 = k0 + GBK;
        if (k1 < kend) {
            int nxt = cur ^ 1;
            char* aD = (char*)As + nxt * (ABUF * 2) + tid * 16;
            char* bD = (char*)Bs + nxt * (BBUF * 2) + tid * 16;
            async_copy16(A + a_off0 + k1, aD);
            async_copy16(A + a_off1 + k1, aD + 4096);
            async_copy16(Bw + b_off0 + k1, bD);
            if constexpr (NT == 128) async_copy16(Bw + b_off1 + k1, bD + 4096);
        }

        const short* Ab = As + cur * ABUF;
        const short* Bb = Bs + cur * BBUF;
        short8 af[AF], bf[4];
#pragma unroll
        for (int t = 0; t < AF; ++t)
            af[t] = *reinterpret_cast<const short8*>(&Ab[(rowbase + t * 16 + lm) * GBK + koff]);
#pragma unroll
        for (int t = 0; t < 4; ++t)
            bf[t] = *reinterpret_cast<const short8*>(&Bb[(colbase + t * 16 + lm) * GBK + koff]);
#pragma unroll
        for (int tm = 0; tm < AF; ++tm)
#pragma unroll
            for (int tn = 0; tn < 4; ++tn)
                acc[tm][tn] = __builtin_amdgcn_mfma_f32_16x16x32_bf16(
                    af[tm], bf[tn], acc[tm][tn], 0, 0, 0);
        cur ^= 1;
    }

    const int rq = (lane >> 4) * 4;
#pragma unroll
    for (int tm = 0; tm < AF; ++tm) {
#pragma unroll
        for (int tn = 0; tn < 4; ++tn) {
            f32x4 v = acc[tm][tn];
            int col = n0 + colbase + tn * 16 + lm;
#pragma unroll
            for (int r = 0; r < 4; ++r) {
                int row = m0 + rowbase + tm * 16 + rq + r;
                float val = v[r];
                if (mode == 0) {
                    if (col < D_INNER) Cf[(size_t)row * D_INNER + col] = val;
                    else               Cz[(size_t)row * D_INNER + (col - D_INNER)] = f2b(val);
                } else if (mode == 1) {
                    Cout[(size_t)row * N + col] = val + res[(size_t)row * N + col];
                } else if (mode == 2) {
                    atomicAdd(&Cf[(size_t)row * N + col], val);
                } else if (mode == 3) {
                    float a = val + bias[col];
                    float sp = (a > 20.f) ? a : log1pf(expf(a));
                    Cf[(size_t)row * N + col] = sp;
                } else {
                    Cf[(size_t)blockIdx.z * 4096 * N + (size_t)row * N + col] = val;
                }
            }
        }
    }
}

// ------------------------------------------------- out = x + P0 + P1 (out-proj reduce)
__global__ void k_reduce_out(const float* __restrict__ x, const float* __restrict__ P,
                             float* __restrict__ out) {
    int i = blockIdx.x * 256 + threadIdx.x;
    float4 a = reinterpret_cast<const float4*>(x)[i];
    float4 p = reinterpret_cast<const float4*>(P)[i];
    float4 q = reinterpret_cast<const float4*>(P + (size_t)4096 * 1024)[i];
    float4 o;
    o.x = a.x + p.x + q.x; o.y = a.y + p.y + q.y;
    o.z = a.z + p.z + q.z; o.w = a.w + p.w + q.w;
    reinterpret_cast<float4*>(out)[i] = o;
}

// ------------------------------------------------- causal depthwise conv + SiLU
__global__ void k_conv(const float* __restrict__ xc, const float* __restrict__ cw,
                       const float* __restrict__ cb, bf16* __restrict__ xcs) {
    size_t idx = (size_t)blockIdx.x * blockDim.x + threadIdx.x;
    int d = (int)(idx & (D_INNER - 1));
    int l = (int)((idx >> 11) & (SEQ - 1));
    float w0 = cw[d * 4 + 0], w1 = cw[d * 4 + 1];
    float w2 = cw[d * 4 + 2], w3 = cw[d * 4 + 3];
    const float* base = xc + idx;
    float acc = cb[d] + w3 * base[0];
    if (l >= 1) acc += w2 * base[-(int)D_INNER];
    if (l >= 2) acc += w1 * base[-2 * (int)D_INNER];
    if (l >= 3) acc += w0 * base[-3 * (int)D_INNER];
    xcs[idx] = f2b(acc / (1.f + __expf(-acc)));   // silu
}

// ------------------------------------------------- scan pass A: per-chunk partials
__global__ __launch_bounds__(256) void k_scan_partialB(
    const float* __restrict__ delta, const bf16* __restrict__ xcs,
    const float* __restrict__ xdbl, const float* __restrict__ A_log,
    bf16* __restrict__ chs, float* __restrict__ sumdl)
{
    __shared__ float Bsh[CHLEN][16];
    const int tid = threadIdx.x;
    const int d = blockIdx.x * 256 + tid;
    const int chunk = blockIdx.y;
    const int b = blockIdx.z;
    const size_t tbase = (size_t)b * SEQ + (size_t)chunk * CHLEN;

    if (tid < 128) {
        int t = tid >> 2, j = (tid & 3) * 4;
        float4 v = *reinterpret_cast<const float4*>(&xdbl[(tbase + t) * XDS + 64 + j]);
        *reinterpret_cast<float4*>(&Bsh[t][j]) = v;
    }
    float An[16];
#pragma unroll
    for (int j = 0; j < 4; ++j) {
        float4 v = *reinterpret_cast<const float4*>(&A_log[(size_t)d * DSTATE + j * 4]);
        An[j * 4 + 0] = -__expf(v.x); An[j * 4 + 1] = -__expf(v.y);
        An[j * 4 + 2] = -__expf(v.z); An[j * 4 + 3] = -__expf(v.w);
    }
    __syncthreads();

    float s[16];
#pragma unroll
    for (int n = 0; n < 16; ++n) s[n] = 0.f;
    float sd = 0.f;
    for (int t = 0; t < CHLEN; ++t) {
        size_t gt = tbase + t;
        float dl = delta[gt * D_INNER + d];
        float u  = b2f(xcs[gt * D_INNER + d]);
        float dlu = dl * u;
        sd += dl;
#pragma unroll
        for (int n = 0; n < 16; ++n) {
            float dA = __expf(dl * An[n]);
            s[n] = fmaf(dA, s[n], dlu * Bsh[t][n]);
        }
    }
    const int pair = b * D_INNER + d;
    bf16* co = chs + ((size_t)pair * NCH + chunk) * DSTATE;
#pragma unroll
    for (int n = 0; n < 16; ++n) co[n] = f2b(s[n]);
    sumdl[(size_t)pair * NCH + chunk] = sd;
}

// ------------------------------------------------- scan pass B: chunk-prefix combine
// sst ALIASES chs: read chunk-sum before writing entry state (same thread+element).
__global__ void k_scan_combineB(const bf16* __restrict__ chs, const float* __restrict__ sumdl,
                                const float* __restrict__ A_log, bf16* __restrict__ sst) {
    int idx = blockIdx.x * 256 + threadIdx.x;
    int pair = idx >> 4;
    int n = idx & 15;
    int d = pair & (D_INNER - 1);
    float An = -__expf(A_log[(size_t)d * DSTATE + n]);
    float s = 0.f;
    for (int c = 0; c < NCH; ++c) {
        size_t o = ((size_t)pair * NCH + c) * DSTATE + n;
        float loc = b2f(chs[o]);
        float ap = __expf(An * sumdl[(size_t)pair * NCH + c]);
        sst[o] = f2b(s);
        s = fmaf(ap, s, loc);
    }
}

// ------------------------------------------------- scan pass C: final y + gate
// yf aliases zbuf elementwise (same-thread read-then-write).
__global__ __launch_bounds__(256) void k_scan_finalB(
    const float* __restrict__ delta, const bf16* __restrict__ xcs,
    const float* __restrict__ xdbl, const bf16* __restrict__ zbuf,
    const float* __restrict__ A_log, const float* __restrict__ Dp,
    const bf16* __restrict__ sst, bf16* __restrict__ yf)
{
    __shared__ float BC[CHLEN][32];   // [t][0:16]=B, [t][16:32]=C
    const int tid = threadIdx.x;
    const int d = blockIdx.x * 256 + tid;
    const int chunk = blockIdx.y;
    const int b = blockIdx.z;
    const size_t tbase = (size_t)b * SEQ + (size_t)chunk * CHLEN;

    {
        int t = tid >> 3, j = (tid & 7) * 4;
        float4 v = *reinterpret_cast<const float4*>(&xdbl[(tbase + t) * XDS + 64 + j]);
        *reinterpret_cast<float4*>(&BC[t][j]) = v;
    }
    float An[16];
#pragma unroll
    for (int j = 0; j < 4; ++j) {
        float4 v = *reinterpret_cast<const float4*>(&A_log[(size_t)d * DSTATE + j * 4]);
        An[j * 4 + 0] = -__expf(v.x); An[j * 4 + 1] = -__expf(v.y);
        An[j * 4 + 2] = -__expf(v.z); An[j * 4 + 3] = -__expf(v.w);
    }
    const int pair = b * D_INNER + d;
    float s[16];
    const bf16* so = sst + ((size_t)pair * NCH + chunk) * DSTATE;
#pragma unroll
    for (int n = 0; n < 16; ++n) s[n] = b2f(so[n]);
    const float Dv = Dp[d];
    __syncthreads();

    for (int t = 0; t < CHLEN; ++t) {
        size_t gt = tbase + t;
        float dl = delta[gt * D_INNER + d];
        float u  = b2f(xcs[gt * D_INNER + d]);
        float dlu = dl * u;
        float y = 0.f;
#pragma unroll
        for (int n = 0; n < 16; ++n) {
            float dA = __expf(dl * An[n]);
            s[n] = fmaf(dA, s[n], dlu * BC[t][n]);
            y = fmaf(s[n], BC[t][16 + n], y);
        }
        float zv = b2f(zbuf[gt * D_INNER + d]);
        float sz = zv / (1.f + __expf(-zv));
        yf[gt * D_INNER + d] = f2b((y + u * Dv) * sz);
    }
}

// ---------------------------------------------------------------- launch
extern "C" void kernel_launch(void* const* d_in, const int* in_sizes, int n_in,
                              void* d_out, int out_size, void* d_ws, size_t ws_size,
                              hipStream_t stream) {
    const float* x      = (const float*)d_in[0];
    const float* ln_g   = (const float*)d_in[1];
    const float* ln_b   = (const float*)d_in[2];
    const float* W_in   = (const float*)d_in[3];
    const float* conv_w = (const float*)d_in[4];
    const float* conv_b = (const float*)d_in[5];
    const float* A_log  = (const float*)d_in[6];
    const float* D_par  = (const float*)d_in[7];
    const float* xpw    = (const float*)d_in[8];
    const float* dtw    = (const float*)d_in[9];
    const float* dtb    = (const float*)d_in[10];
    const float* W_out  = (const float*)d_in[11];
    float* out = (float*)d_out;

    char* ws = (char*)d_ws;
    // workspace (79,953,920 B), stage-lifetime aliased:
    //  [0,        8388608)  xn bf16 -> chs/sst bf16 (scan) -> wOutb bf16 (after scan_final)
    //  [8388608, 41943040)  xc fp32 -> delta fp32 -> P0 fp32 @8388608 + P1 fp32 @25165824
    //  [41943040,58720256)  z bf16  <- yf aliases z
    //  [58720256,75497472)  wInb bf16 -> xcs bf16
    //  [75497472,77594624)  xdbl fp32 (4096x128)
    //  [77594624,78643200)  sumdl; [78643200..] drb, dtwb, xpwb
    bf16*  xn    = (bf16*)(ws + 0);
    bf16*  chs   = (bf16*)(ws + 0);
    bf16*  sst   = chs;
    short* wOutb = (short*)(ws + 0);           // after scan kernels are done
    float* xc    = (float*)(ws + 8388608);
    float* delta = xc;
    float* P0    = (float*)(ws + 8388608);     // after delta is dead (post scan_final)
    bf16*  z     = (bf16*)(ws + 41943040);
    bf16*  yf    = z;
    short* wInb  = (short*)(ws + 58720256);
    bf16*  xcs   = (bf16*)(ws + 58720256);
    float* xdbl  = (float*)(ws + 75497472);
    float* sumdl = (float*)(ws + 77594624);
    short* drb   = (short*)(ws + 78643200);
    short* dtwb  = (short*)(ws + 79167488);
    short* xpwb  = (short*)(ws + 79429632);

    // fused prep: LN + f2b(W_in) + prep(xpw) + f2b(dtw) + zero(xdbl)
    k_prep<<<9088, 256, 0, stream>>>(x, ln_g, ln_b, xn, W_in, wInb, xpw, xpwb, dtw, dtwb, xdbl);
    // in-proj GEMM: 4096 x 4096 x 1024, NT=64 -> 2048 blocks
    k_gemm_mfma<64><<<dim3(4096 / 64, 32, 1), 256, 0, stream>>>(
        (const short*)xn, wInb, 2 * D_INNER, D_MODEL, 0, xc, z, nullptr, nullptr, nullptr);
    k_conv<<<(NTOK * D_INNER) / 256, 256, 0, stream>>>(xc, conv_w, conv_b, xcs);
    // xproj GEMM: 4096 x 128 x 2048, NT=64, split-K=8 atomic -> 512 blocks
    k_gemm_mfma<64><<<dim3(2, 32, 8), 256, 0, stream>>>(
        (const short*)xcs, xpwb, XDS, D_INNER, 2, xdbl, nullptr, nullptr, nullptr, nullptr);
    // delta GEMM: 4096 x 2048 x 64, NT=64 -> 1024 blocks, softplus epilogue
    k_extract_dr<<<(NTOK * DTRANK / 4) / 256, 256, 0, stream>>>(xdbl, drb);
    k_gemm_mfma<64><<<dim3(D_INNER / 64, 32, 1), 256, 0, stream>>>(
        drb, dtwb, D_INNER, DTRANK, 3, delta, nullptr, nullptr, nullptr, dtb);
    // selective scan (3-pass, register-state formulation)
    k_scan_partialB<<<dim3(D_INNER / 256, NCH, BSZ), 256, 0, stream>>>(
        delta, xcs, xdbl, A_log, chs, sumdl);
    k_scan_combineB<<<(NPAIR * DSTATE) / 256, 256, 0, stream>>>(chs, sumdl, A_log, sst);
    k_scan_finalB<<<dim3(D_INNER / 256, NCH, BSZ), 256, 0, stream>>>(
        delta, xcs, xdbl, z, A_log, D_par, sst, yf);
    // out-proj GEMM: 4096 x 1024 x 2048, NT=64, split-K=2 -> 1024 blocks + reduce
    k_f2b<<<(D_MODEL * D_INNER / 4) / 256, 256, 0, stream>>>(W_out, wOutb);
    k_gemm_mfma<64><<<dim3(D_MODEL / 64, 32, 2), 256, 0, stream>>>(
        (const short*)yf, wOutb, D_MODEL, D_INNER, 4, P0, nullptr, nullptr, nullptr, nullptr);
    k_reduce_out<<<(NTOK * D_MODEL / 4) / 256, 256, 0, stream>>>(x, P0, out);
}